// Round 11
// baseline (257.400 us; speedup 1.0000x reference)
//
#include <hip/hip_runtime.h>

#define NPOS 576      // B*oH*oW
#define KTOT 144      // KH*KW*IC
#define NOC 32
#define NP 16
#define OCP 512
#define CHUNK 16
#define NCHUNK 9      // KTOT / CHUNK
#define EPSF 1e-7f
#define LOG2PIF 1.83787706640934548356f

// 3-pass fused EM routing (f32 in / f32 out):
//  pass 0: A0 with uniform R (w = a[k]/32), fused s0,s1,s2
//  pass 1: transition iter0->1: logits+softmax+accumulate, V read once (regs)
//  pass 2: transition iter1->2: same
// sigma via cancellation: sig = s2*inv - mu^2  (diff from ref: ~mu^2*eps*inv ~ 1e-7)
__global__ __launch_bounds__(512) void em_routing(
    const float* __restrict__ Vf, const float* __restrict__ Af,
    const float* __restrict__ Bup, const float* __restrict__ Bap,
    float* __restrict__ out)
{
  const int pos = blockIdx.x;           // 0..575
  const int t   = (int)threadIdx.x;     // 0..511
  const int oc  = t >> 4;
  const int p   = t & 15;

  __shared__ float sRw[KTOT][NOC];      // routing weights * a
  __shared__ float sA[KTOT];
  __shared__ float sRed[OCP];           // log-sigma reduction
  __shared__ float sX[NOC];
  __shared__ float sBase[NOC];
  __shared__ float sLogit[CHUNK][NOC];  // per-chunk raw quad sums

  const size_t vbase = (size_t)pos * (KTOT * OCP);
  const float Bu = Bup[oc];
  const float Ba = Bap[oc];

  if (t < KTOT) sA[t] = Af[pos * KTOT + t];
  __syncthreads();

  // ---- pass 0: A0 under uniform R (w = a[k]/32); fused moments ----
  float s0 = 0.f, s1 = 0.f, s2 = 0.f;
  for (int k = 0; k < KTOT; ++k) {
    const float v = Vf[vbase + k * OCP + t];
    const float w = sA[k] * (1.0f / 32.0f);
    s0 += w; s1 += w * v; s2 += w * v * v;
  }

  float mu = 0.f, sig = 1.f, aout = 0.5f;

  for (int it = 0; it < 3; ++it) {
    const float lam = (it == 0) ? 5e-4f : (it == 1) ? 9.75e-4f : 1.42625e-3f;

    const float inv = 1.0f / (s0 + EPSF);
    mu  = s1 * inv;
    sig = fmaxf(s2 * inv - mu * mu, 1e-30f);   // cancellation form + log guard

    // L = sum_p log(sigma) over the 16-lane p-group (via LDS)
    sRed[t] = logf(sig);
    __syncthreads();                          // B1
    float L = 0.f;
    #pragma unroll
    for (int q = 0; q < NP; ++q) L += sRed[oc * NP + q];

    const float x = lam * (Ba - s0 * (16.0f * Bu + 0.5f * L));
    if (p == 0) sX[oc] = x;
    __syncthreads();                          // B2
    float ss = 0.f;
    #pragma unroll
    for (int j = 0; j < NOC; ++j) ss += sX[j] * sX[j];
    const float nrm = fmaxf(sqrtf(ss), 1e-12f);
    aout = 1.0f / (1.0f + expf(-x / nrm));

    if (it == 2) break;                       // final E-step dead in reference

    const float c0 = 1.0f / (2.0f * sig + EPSF);
    if (p == 0)
      sBase[oc] = logf(aout) + (-0.5f * (16.0f * LOG2PIF + L) + EPSF);
    __syncthreads();                          // B3 (sBase ready; sRed free)

    // ---- fused transition: logits -> softmax -> next moments, 1 V pass ----
    float n0 = 0.f, n1 = 0.f, n2 = 0.f;
    for (int c = 0; c < NCHUNK; ++c) {
      const int k0 = c * CHUNK;
      float vloc[CHUNK];

      // phase 1: own-column quad terms, 16-lane reduce -> sLogit
      #pragma unroll
      for (int r = 0; r < CHUNK; ++r) {
        const float v = Vf[vbase + (size_t)(k0 + r) * OCP + t];
        vloc[r] = v;
        const float d = v - mu;
        float e = d * d * c0;
        #pragma unroll
        for (int m = 1; m < 16; m <<= 1) e += __shfl_xor(e, m, 16);
        if (p == 0) sLogit[r][oc] = e;
      }
      __syncthreads();                        // B-a

      // phase 2: softmax over oc per row; fold a[k]; write Rw
      {
        const int r = t >> 5, j = t & 31;
        const float val = sBase[j] - sLogit[r][j];
        float mx = val;
        #pragma unroll
        for (int m = 1; m < 32; m <<= 1) mx = fmaxf(mx, __shfl_xor(mx, m, 32));
        const float e = expf(val - mx);
        float sum = e;
        #pragma unroll
        for (int m = 1; m < 32; m <<= 1) sum += __shfl_xor(sum, m, 32);
        sRw[k0 + r][j] = e * (sA[k0 + r] / sum);
      }
      __syncthreads();                        // B-b

      // phase 3: accumulate next-iteration moments from registers
      #pragma unroll
      for (int r = 0; r < CHUNK; ++r) {
        const float w = sRw[k0 + r][oc];
        const float v = vloc[r];
        n0 += w; n1 += w * v; n2 += w * v * v;
      }
    }
    s0 = n0; s1 = n1; s2 = n2;
  }

  // ---- outputs (f32): mu [0:294912] | a_out [294912:313344] | sigma [...] ----
  const size_t base_mu = (size_t)pos * OCP + t;
  out[base_mu]           = mu;
  out[313344u + base_mu] = sig;
  if (p == 0) out[294912u + (size_t)pos * NOC + oc] = aout;
}

extern "C" void kernel_launch(void* const* d_in, const int* in_sizes, int n_in,
                              void* d_out, int out_size, void* d_ws, size_t ws_size,
                              hipStream_t stream) {
  em_routing<<<NPOS, 512, 0, stream>>>((const float*)d_in[0], (const float*)d_in[1],
                                       (const float*)d_in[2], (const float*)d_in[3],
                                       (float*)d_out);
}

// Round 12
// 96.435 us; speedup vs baseline: 2.6692x; 2.6692x over previous
//
#include <hip/hip_runtime.h>

#define NPOS 576      // B*oH*oW
#define KTOT 144      // KH*KW*IC
#define NOC 32
#define NP 16
#define OCP 512       // columns per position (32 oc x 16 p)
#define NCQ 128       // column-quads per row (OCP/4)
#define CHUNK 48      // rows per chunk
#define RPT 12        // rows per thread per chunk (CHUNK/4 row-slots)
#define NCHUNK 3      // KTOT / CHUNK
#define EPSF 1e-7f
#define LOG2PIF 1.83787706640934548356f

// Latency-optimized fused EM routing (f32 in/out):
//  - thread owns a column-QUAD (float4 loads/stores, 1KB/wave/instr)
//  - 3 V passes total; V cached in registers across logit->moment (vloc[12])
//  - 48-row chunks, double-buffered sL -> 2 barriers/chunk
//  - p-reduce: width-4 shuffles; softmax: width-32 shuffles
__global__ __launch_bounds__(512, 4) void em_routing(
    const float* __restrict__ Vf, const float* __restrict__ Af,
    const float* __restrict__ Bup, const float* __restrict__ Bap,
    float* __restrict__ out)
{
  const int pos = blockIdx.x;           // 0..575
  const int t   = (int)threadIdx.x;     // 0..511
  const int c   = t & 127;              // column-quad: columns 4c..4c+3
  const int rs  = t >> 7;               // row-slot 0..3
  const int oc  = c >> 2;

  __shared__ float sA[KTOT];
  __shared__ float sL[2][CHUNK][NOC];   // logits -> weights, double-buffered
  __shared__ float sRed[4][NCQ][9];     // cross-row-slot moment reduction
  __shared__ float sX[NOC];
  __shared__ float sBase[NOC];

  const float4* __restrict__ V4 =
      (const float4*)(Vf + (size_t)pos * (KTOT * OCP));

  if (t < KTOT) sA[t] = Af[pos * KTOT + t];
  const float Bu = Bup[oc];
  const float Ba = Bap[oc];
  __syncthreads();

  // ---- pass 0: moments under uniform R (w = a[k]/32) ----
  float  s0 = 0.f;
  float4 s1 = {0.f,0.f,0.f,0.f}, s2 = {0.f,0.f,0.f,0.f};
  #pragma unroll 12
  for (int r = 0; r < 36; ++r) {
    const int k = rs + 4 * r;
    const float w = sA[k] * (1.0f / 32.0f);
    const float4 v = V4[k * NCQ + c];
    s0 += w;
    s1.x += w * v.x; s1.y += w * v.y; s1.z += w * v.z; s1.w += w * v.w;
    s2.x += w * v.x * v.x; s2.y += w * v.y * v.y;
    s2.z += w * v.z * v.z; s2.w += w * v.w * v.w;
  }

  float4 mu, sig;
  float aout = 0.5f;

  for (int it = 0; it < 3; ++it) {
    const float lam = (it == 0) ? 5e-4f : (it == 1) ? 9.75e-4f : 1.42625e-3f;

    // ---- cross-row-slot reduction of {s0, s1, s2} ----
    sRed[rs][c][0] = s0;
    sRed[rs][c][1] = s1.x; sRed[rs][c][2] = s1.y;
    sRed[rs][c][3] = s1.z; sRed[rs][c][4] = s1.w;
    sRed[rs][c][5] = s2.x; sRed[rs][c][6] = s2.y;
    sRed[rs][c][7] = s2.z; sRed[rs][c][8] = s2.w;
    __syncthreads();
    {
      float a0 = 0.f, a1 = 0.f, a2 = 0.f, a3 = 0.f, a4 = 0.f,
            a5 = 0.f, a6 = 0.f, a7 = 0.f, a8 = 0.f;
      #pragma unroll
      for (int q = 0; q < 4; ++q) {
        a0 += sRed[q][c][0];
        a1 += sRed[q][c][1]; a2 += sRed[q][c][2];
        a3 += sRed[q][c][3]; a4 += sRed[q][c][4];
        a5 += sRed[q][c][5]; a6 += sRed[q][c][6];
        a7 += sRed[q][c][7]; a8 += sRed[q][c][8];
      }
      s0 = a0;
      s1.x = a1; s1.y = a2; s1.z = a3; s1.w = a4;
      s2.x = a5; s2.y = a6; s2.z = a7; s2.w = a8;
    }

    const float inv = 1.0f / (s0 + EPSF);
    mu.x = s1.x * inv; mu.y = s1.y * inv; mu.z = s1.z * inv; mu.w = s1.w * inv;
    sig.x = fmaxf(s2.x * inv - mu.x * mu.x, 1e-30f);
    sig.y = fmaxf(s2.y * inv - mu.y * mu.y, 1e-30f);
    sig.z = fmaxf(s2.z * inv - mu.z * mu.z, 1e-30f);
    sig.w = fmaxf(s2.w * inv - mu.w * mu.w, 1e-30f);

    // L = sum over 16 p of log(sigma): own 4 + width-4 butterfly
    float Lown = logf(sig.x) + logf(sig.y) + logf(sig.z) + logf(sig.w);
    float L1 = Lown + __shfl_xor(Lown, 1, 4);
    const float L = L1 + __shfl_xor(L1, 2, 4);

    const float x = lam * (Ba - s0 * (16.0f * Bu + 0.5f * L));
    if (rs == 0 && (c & 3) == 0) sX[oc] = x;
    __syncthreads();                        // Bx: sX ready (also fences sRed)
    float ss = 0.f;
    #pragma unroll
    for (int j = 0; j < NOC; ++j) ss += sX[j] * sX[j];
    const float nrm = fmaxf(sqrtf(ss), 1e-12f);
    aout = 1.0f / (1.0f + expf(-x / nrm));

    if (it == 2) break;                     // final E-step dead in reference

    float4 c0q;
    c0q.x = 1.0f / (2.0f * sig.x + EPSF);
    c0q.y = 1.0f / (2.0f * sig.y + EPSF);
    c0q.z = 1.0f / (2.0f * sig.z + EPSF);
    c0q.w = 1.0f / (2.0f * sig.w + EPSF);
    if (rs == 0 && (c & 3) == 0)
      sBase[oc] = logf(aout) + (-0.5f * (16.0f * LOG2PIF + L) + EPSF);
    __syncthreads();                        // Bb: sBase ready

    // ---- fused transition: 48-row chunks, V read once (reg-cached) ----
    float  n0 = 0.f;
    float4 n1 = {0.f,0.f,0.f,0.f}, n2 = {0.f,0.f,0.f,0.f};
    for (int ch = 0; ch < NCHUNK; ++ch) {
      const int b = ch & 1;
      const int kbase = ch * CHUNK;
      float4 vloc[RPT];
      #pragma unroll
      for (int r = 0; r < RPT; ++r)
        vloc[r] = V4[(kbase + rs + 4 * r) * NCQ + c];

      // logits: quad term over own 4 p, width-4 reduce -> sL[b][k][oc]
      #pragma unroll
      for (int r = 0; r < RPT; ++r) {
        const float4 v = vloc[r];
        const float dx = v.x - mu.x, dy = v.y - mu.y,
                    dz = v.z - mu.z, dw = v.w - mu.w;
        float q = dx * dx * c0q.x + dy * dy * c0q.y
                + dz * dz * c0q.z + dw * dw * c0q.w;
        q += __shfl_xor(q, 1, 4);
        q += __shfl_xor(q, 2, 4);
        if ((c & 3) == 0) sL[b][rs + 4 * r][oc] = q;
      }
      __syncthreads();                      // B1: logits ready

      // softmax over oc per row; fold a[k]; in-place -> weights
      #pragma unroll
      for (int j = 0; j < 3; ++j) {
        const int idx = t + 512 * j;
        const int kl = idx >> 5, o = idx & 31;
        const float val = sBase[o] - sL[b][kl][o];
        float mx = val;
        #pragma unroll
        for (int m = 1; m < 32; m <<= 1) mx = fmaxf(mx, __shfl_xor(mx, m, 32));
        const float e = expf(val - mx);
        float sum = e;
        #pragma unroll
        for (int m = 1; m < 32; m <<= 1) sum += __shfl_xor(sum, m, 32);
        sL[b][kl][o] = e * (sA[kbase + kl] / sum);
      }
      __syncthreads();                      // B2: weights ready

      // moments from cached registers
      #pragma unroll
      for (int r = 0; r < RPT; ++r) {
        const float w = sL[b][rs + 4 * r][oc];
        const float4 v = vloc[r];
        n0 += w;
        n1.x += w * v.x; n1.y += w * v.y; n1.z += w * v.z; n1.w += w * v.w;
        n2.x += w * v.x * v.x; n2.y += w * v.y * v.y;
        n2.z += w * v.z * v.z; n2.w += w * v.w * v.w;
      }
    }
    s0 = n0; s1 = n1; s2 = n2;
  }

  // ---- outputs (f32): mu [0:294912] | a_out [294912:313344] | sigma [...] ----
  if (rs == 0) {
    float4* __restrict__ out4 = (float4*)out;
    out4[(size_t)pos * NCQ + c]         = mu;    // mu block, f4 index
    out4[78336u + (size_t)pos * NCQ + c] = sig;  // sigma block (313344/4)
    if ((c & 3) == 0) out[294912u + (size_t)pos * NOC + oc] = aout;
  }
}

extern "C" void kernel_launch(void* const* d_in, const int* in_sizes, int n_in,
                              void* d_out, int out_size, void* d_ws, size_t ws_size,
                              hipStream_t stream) {
  em_routing<<<NPOS, 512, 0, stream>>>((const float*)d_in[0], (const float*)d_in[1],
                                       (const float*)d_in[2], (const float*)d_in[3],
                                       (float*)d_out);
}